// Round 1
// 5145.701 us; speedup vs baseline: 1.3421x; 1.3421x over previous
//
#include <hip/hip_runtime.h>
#include <cstdint>
#include <cstddef>

typedef _Float16 half_t;
typedef _Float16 half2_t __attribute__((ext_vector_type(2)));
typedef _Float16 half8_t __attribute__((ext_vector_type(8)));
typedef float   float4_t __attribute__((ext_vector_type(4)));

#define L_N 2
#define B_N 32
#define S_N 2048
#define H_N 256
#define G_N 1024            // 4H
#define M_N (B_N*S_N)       // 65536

// ---- multi-block recurrence geometry ----
#define NB 8                 // blocks per chain (cell slices of 32 cells)
#define RING_R 2             // ring slots; peer skew is provably <=1 step
#define RING_BYTES (B_N*RING_R*128*8)   // 32 chains x 2 slots x 128 u64 = 64 KiB

// ws layout (bytes)
#define WS_A0   0ull                 // fp16 [M][H]: layer-0 A; later reused as h0 sequence
#define WS_XP   33554432ull          // fp16 [M][G]: input projection, packed [m][cell][4]
#define WS_WI   167772160ull         // fp16 [L][G][H]
#define WS_WH   168820736ull         // fp16 [L][G][H]
#define WS_BSUM 169869312ull         // f32 [L][G]  (b_ih + b_hh)
#define WS_RING 169877504ull         // u64 ring[B][RING_R][128] tagged h pairs

__global__ void cvt_f32_f16(const float* __restrict__ in, half_t* __restrict__ out, int n){
  int i = blockIdx.x*256 + threadIdx.x;
  if (i < n) out[i] = (half_t)in[i];
}

__global__ void make_bsum(const float* __restrict__ bi, const float* __restrict__ bh,
                          float* __restrict__ bs, int n){
  int i = blockIdx.x*256 + threadIdx.x;
  if (i < n) bs[i] = bi[i] + bh[i];
}

// XP[m, cell, gate] = sum_k A[m,k] * W[gate*256+cell, k] + bsum[...]
__global__ __launch_bounds__(256) void gemm_xp(
    const half_t* __restrict__ A, const half_t* __restrict__ W,
    const float* __restrict__ bsum, half_t* __restrict__ XP)
{
  const int wave = threadIdx.x >> 6;
  const int lane = threadIdx.x & 63;
  const int l15 = lane & 15, quad = lane >> 4;
  const int m0 = blockIdx.x*64 + wave*16;
  const int n0 = blockIdx.y*64;
  float4_t acc[4] = {{0,0,0,0},{0,0,0,0},{0,0,0,0},{0,0,0,0}};
  const half_t* arow = A + (size_t)(m0 + l15)*H_N + quad*8;
  const half_t* brow[4];
  #pragma unroll
  for (int nt=0; nt<4; ++nt)
    brow[nt] = W + (size_t)(n0 + nt*16 + l15)*H_N + quad*8;
  #pragma unroll
  for (int k0=0; k0<H_N; k0+=32){
    half8_t af = *(const half8_t*)(arow + k0);
    #pragma unroll
    for (int nt=0; nt<4; ++nt){
      half8_t bf = *(const half8_t*)(brow[nt] + k0);
      acc[nt] = __builtin_amdgcn_mfma_f32_16x16x32_f16(af, bf, acc[nt], 0, 0, 0);
    }
  }
  #pragma unroll
  for (int nt=0; nt<4; ++nt){
    const int col = n0 + nt*16 + l15;          // gate row g in [0,1024)
    const int cell = col & 255, gate = col >> 8;
    const float bs = bsum[col];
    #pragma unroll
    for (int r=0; r<4; ++r){
      XP[(size_t)(m0 + quad*4 + r)*G_N + cell*4 + gate] = (half_t)(acc[nt][r] + bs);
    }
  }
}

__device__ __forceinline__ float sigf(float x){ return 1.f/(1.f + __expf(-x)); }
__device__ __forceinline__ float tanh_f(float x){ return 1.f - 2.f/(__expf(2.f*x) + 1.f); }

// Multi-block LSTM recurrence: 256 blocks = 32 chains x 8 cell-slices.
// Block (c = bid&31, s = bid>>5) owns cells [s*32, s*32+32) of chain c; the
// &31/>>5 split keeps a chain's 8 slices on one XCD (bid%8 const) - perf
// heuristic only. Weights fully VGPR-resident (32 u32/thread). Cross-block h
// exchange: one u64 atom per h-pair = {tag=t+1 | 2xfp16}, relaxed agent-scope
// atomics (write-through to coherence point; data+flag indivisible -> no
// fences). Ring of 2 step-slots per chain; peer skew <=1 step so slot (t-1)%2
// is fully consumed before slot t%2 is overwritten. Ring memset to 0 before
// each launch -> replay-safe (tag 0 never matches an expected tag >=1).
__global__ __launch_bounds__(512) void lstm_rec_mb(
    const uint32_t* __restrict__ Wp,   // fp16-pair view of Wh [1024][128]
    const half_t*  __restrict__ xp,    // [M][1024] packed [m][cell][4], biases folded
    unsigned long long* __restrict__ ring,
    half_t* __restrict__ h16,          // layer-0 h sequence out (fp16)
    float*  __restrict__ h32,          // layer-1 h sequence out (fp32, = d_out x)
    float*  __restrict__ hT, float* __restrict__ cT, int wr32)
{
  __shared__ __align__(16) uint32_t hp[128];   // staged h pairs (full 256-cell h)
  __shared__ float red[4][128];                // K-quarter partial sums
  const int tid = threadIdx.x;
  const int kq = tid >> 7;        // K-quarter: pairs [kq*32, kq*32+32)
  const int r  = tid & 127;       // row within slice: gate g = r>>5, cell cl = r&31
  const int b  = blockIdx.x & 31;
  const int s  = blockIdx.x >> 5;
  const int g  = r >> 5;
  const int cl = r & 31;
  const int cell = s*32 + cl;

  // VGPR-resident weight slice: row (g*256+cell), pairs [kq*32, kq*32+32)
  uint32_t w[32];
  {
    const uint32_t* wp = Wp + (size_t)(g*256 + cell)*128 + kq*32;
    #pragma unroll
    for (int i=0;i<32;++i) w[i] = wp[i];
  }

  unsigned long long* rg = ring + (size_t)b*(RING_R*128);
  const size_t base = (size_t)b * S_N;
  float cstate = 0.f;

  if (tid < 128) hp[tid] = 0u;     // h(-1) = 0
  __syncthreads();

  for (int t=0; t<S_N; ++t){
    // xp prefetch for this step's activation (independent of h) - issue early
    uint2 xv = {0u,0u};
    if (tid < 32) xv = *(const uint2*)(xp + (base+t)*G_N + (size_t)(s*32 + tid)*4);

    if (t > 0){
      if (tid < 128){
        unsigned long long* p = rg + (size_t)((t-1)&(RING_R-1))*128 + tid;
        const unsigned long long tag = (unsigned long long)(unsigned)t;  // = (t-1)+1
        unsigned long long v;
        do { v = __hip_atomic_load(p, __ATOMIC_RELAXED, __HIP_MEMORY_SCOPE_AGENT); }
        while ((v >> 32) != tag);
        hp[tid] = (uint32_t)v;
      }
      __syncthreads();             // B1: h staged (also WAR-protects hp/red)
    }

    // 32 fdot2 over this thread's K-quarter, 4 independent accumulation streams
    const uint4* h4 = (const uint4*)&hp[kq*32];
    float a0=0.f,a1=0.f,a2=0.f,a3=0.f;
    #pragma unroll
    for (int i=0;i<8;++i){
      const uint4 hh = h4[i];
      a0 = __builtin_amdgcn_fdot2(__builtin_bit_cast(half2_t, w[4*i+0]), __builtin_bit_cast(half2_t, hh.x), a0, false);
      a1 = __builtin_amdgcn_fdot2(__builtin_bit_cast(half2_t, w[4*i+1]), __builtin_bit_cast(half2_t, hh.y), a1, false);
      a2 = __builtin_amdgcn_fdot2(__builtin_bit_cast(half2_t, w[4*i+2]), __builtin_bit_cast(half2_t, hh.z), a2, false);
      a3 = __builtin_amdgcn_fdot2(__builtin_bit_cast(half2_t, w[4*i+3]), __builtin_bit_cast(half2_t, hh.w), a3, false);
    }
    red[kq][r] = (a0+a1)+(a2+a3);
    __syncthreads();               // B2: partials visible

    if (tid < 32){
      const half2_t x01 = __builtin_bit_cast(half2_t, xv.x);
      const half2_t x23 = __builtin_bit_cast(half2_t, xv.y);
      const float s0 = red[0][tid]    + red[1][tid]    + red[2][tid]    + red[3][tid]    + (float)x01.x;
      const float s1 = red[0][32+tid] + red[1][32+tid] + red[2][32+tid] + red[3][32+tid] + (float)x01.y;
      const float s2 = red[0][64+tid] + red[1][64+tid] + red[2][64+tid] + red[3][64+tid] + (float)x23.x;
      const float s3 = red[0][96+tid] + red[1][96+tid] + red[2][96+tid] + red[3][96+tid] + (float)x23.y;
      const float gi = sigf(s0);
      const float gf = sigf(s1);
      const float gg = tanh_f(s2);
      const float go = sigf(s3);
      cstate = gf*cstate + gi*gg;
      const float h = go * tanh_f(cstate);
      const half_t hv = (half_t)h;
      const int cme = s*32 + tid;

      // publish FIRST (critical path): lanes 0..15 store tagged pairs
      const int hu  = (int)__builtin_bit_cast(unsigned short, hv);
      const int plo = __shfl(hu, 2*tid,   64);
      const int phi = __shfl(hu, 2*tid+1, 64);
      if (tid < 16){
        const unsigned long long val =
            ((unsigned long long)(unsigned)(t+1) << 32)
          | (unsigned long long)((((unsigned)phi & 0xffffu) << 16) | ((unsigned)plo & 0xffffu));
        __hip_atomic_store(rg + (size_t)(t&(RING_R-1))*128 + s*16 + tid, val,
                           __ATOMIC_RELAXED, __HIP_MEMORY_SCOPE_AGENT);
      }
      // sequence outputs (plain stores; consumed after kernel boundary)
      if (wr32) h32[(base+t)*H_N + cme] = h;
      else      h16[(base+t)*H_N + cme] = hv;
      if (t == S_N-1){ hT[b*H_N + cme] = h; cT[b*H_N + cme] = cstate; }
    }
    // no trailing barrier: next-iter LDS writes are ordered behind B1/B2
  }
}

extern "C" void kernel_launch(void* const* d_in, const int* in_sizes, int n_in,
                              void* d_out, int out_size, void* d_ws, size_t ws_size,
                              hipStream_t stream)
{
  const float* x   = (const float*)d_in[0];
  const float* Wih = (const float*)d_in[1];
  const float* bih = (const float*)d_in[2];
  const float* Whh = (const float*)d_in[3];
  const float* bhh = (const float*)d_in[4];
  float* out = (float*)d_out;

  char* ws = (char*)d_ws;
  half_t* A0   = (half_t*)(ws + WS_A0);    // layer-0 fp16 input; reused as h0 sequence
  half_t* XP   = (half_t*)(ws + WS_XP);
  half_t* Wi16 = (half_t*)(ws + WS_WI);
  half_t* Wh16 = (half_t*)(ws + WS_WH);
  float*  bsum = (float*)(ws + WS_BSUM);
  unsigned long long* ring = (unsigned long long*)(ws + WS_RING);

  cvt_f32_f16<<<dim3(M_N*H_N/256), dim3(256), 0, stream>>>(x, A0, M_N*H_N);
  cvt_f32_f16<<<dim3(L_N*G_N*H_N/256), dim3(256), 0, stream>>>(Wih, Wi16, L_N*G_N*H_N);
  cvt_f32_f16<<<dim3(L_N*G_N*H_N/256), dim3(256), 0, stream>>>(Whh, Wh16, L_N*G_N*H_N);
  make_bsum<<<dim3(L_N*G_N/256), dim3(256), 0, stream>>>(bih, bhh, bsum, L_N*G_N);

  float* hT = out + (size_t)M_N*H_N;       // hs [2][32][256]
  float* cT = hT + (size_t)L_N*B_N*H_N;    // cs [2][32][256]

  // ---- layer 0
  hipMemsetAsync(ring, 0, RING_BYTES, stream);
  gemm_xp<<<dim3(M_N/64, G_N/64), dim3(256), 0, stream>>>(A0, Wi16, bsum, XP);
  lstm_rec_mb<<<dim3(B_N*NB), dim3(512), 0, stream>>>(
      (const uint32_t*)Wh16, XP, ring, A0 /*h0 seq overwrites dead A0*/, nullptr,
      hT, cT, 0);

  // ---- layer 1
  gemm_xp<<<dim3(M_N/64, G_N/64), dim3(256), 0, stream>>>(A0, Wi16 + (size_t)G_N*H_N, bsum + G_N, XP);
  hipMemsetAsync(ring, 0, RING_BYTES, stream);
  lstm_rec_mb<<<dim3(B_N*NB), dim3(512), 0, stream>>>(
      (const uint32_t*)(Wh16 + (size_t)G_N*H_N), XP, ring, nullptr, out,
      hT + B_N*H_N, cT + B_N*H_N, 1);
}

// Round 2
// 4272.511 us; speedup vs baseline: 1.6164x; 1.2044x over previous
//
#include <hip/hip_runtime.h>
#include <cstdint>
#include <cstddef>

typedef _Float16 half_t;
typedef _Float16 half2_t __attribute__((ext_vector_type(2)));
typedef _Float16 half8_t __attribute__((ext_vector_type(8)));
typedef float   float4_t __attribute__((ext_vector_type(4)));

#define L_N 2
#define B_N 32
#define S_N 2048
#define H_N 256
#define G_N 1024            // 4H
#define M_N (B_N*S_N)       // 65536

// ---- fused recurrence geometry ----
// 256 blocks = 32 chains x 8 cell-slices; each block advances layer0 step t and
// layer1 step t-1 in the same iteration (software wavefront pipeline).
#define RING_R 4             // ring slots; intra-ring peer skew provably <=1 step
#define RING_BYTES (B_N*RING_R*128*8)   // 128 KiB per ring

// ws layout (bytes)
#define WS_A0   0ull                 // fp16 [M][H]: layer-0 input (f32->f16)
#define WS_XP   33554432ull          // fp16 [M][G]: layer-0 input projection, packed [m][cell][4]
#define WS_WI   167772160ull         // fp16 [L][G][H]
#define WS_WH   168820736ull         // fp16 [L][G][H]
#define WS_BSUM 169869312ull         // f32 [L][G]  (b_ih + b_hh)
#define WS_HP0  169877504ull         // u64 ring [B][RING_R][128] tagged h0 pairs
#define WS_HP1  170008576ull         // u64 ring [B][RING_R][128] tagged h1 pairs

__global__ void cvt_f32_f16(const float* __restrict__ in, half_t* __restrict__ out, int n){
  int i = blockIdx.x*256 + threadIdx.x;
  if (i < n) out[i] = (half_t)in[i];
}

__global__ void make_bsum(const float* __restrict__ bi, const float* __restrict__ bh,
                          float* __restrict__ bs, int n){
  int i = blockIdx.x*256 + threadIdx.x;
  if (i < n) bs[i] = bi[i] + bh[i];
}

// XP[m, cell, gate] = sum_k A[m,k] * W[gate*256+cell, k] + bsum[...]
__global__ __launch_bounds__(256) void gemm_xp(
    const half_t* __restrict__ A, const half_t* __restrict__ W,
    const float* __restrict__ bsum, half_t* __restrict__ XP)
{
  const int wave = threadIdx.x >> 6;
  const int lane = threadIdx.x & 63;
  const int l15 = lane & 15, quad = lane >> 4;
  const int m0 = blockIdx.x*64 + wave*16;
  const int n0 = blockIdx.y*64;
  float4_t acc[4] = {{0,0,0,0},{0,0,0,0},{0,0,0,0},{0,0,0,0}};
  const half_t* arow = A + (size_t)(m0 + l15)*H_N + quad*8;
  const half_t* brow[4];
  #pragma unroll
  for (int nt=0; nt<4; ++nt)
    brow[nt] = W + (size_t)(n0 + nt*16 + l15)*H_N + quad*8;
  #pragma unroll
  for (int k0=0; k0<H_N; k0+=32){
    half8_t af = *(const half8_t*)(arow + k0);
    #pragma unroll
    for (int nt=0; nt<4; ++nt){
      half8_t bf = *(const half8_t*)(brow[nt] + k0);
      acc[nt] = __builtin_amdgcn_mfma_f32_16x16x32_f16(af, bf, acc[nt], 0, 0, 0);
    }
  }
  #pragma unroll
  for (int nt=0; nt<4; ++nt){
    const int col = n0 + nt*16 + l15;          // gate row g in [0,1024)
    const int cell = col & 255, gate = col >> 8;
    const float bs = bsum[col];
    #pragma unroll
    for (int r=0; r<4; ++r){
      XP[(size_t)(m0 + quad*4 + r)*G_N + cell*4 + gate] = (half_t)(acc[nt][r] + bs);
    }
  }
}

__device__ __forceinline__ float sigf(float x){ return 1.f/(1.f + __expf(-x)); }
__device__ __forceinline__ float tanh_f(float x){ return 1.f - 2.f/(__expf(2.f*x) + 1.f); }

__device__ __forceinline__ unsigned long long ring_poll(
    const unsigned long long* p, unsigned long long tag)
{
  unsigned long long v;
  do { v = __hip_atomic_load(p, __ATOMIC_RELAXED, __HIP_MEMORY_SCOPE_AGENT); }
  while ((v >> 32) != tag);
  return v;
}

// Fused 2-layer LSTM recurrence, wavefront-pipelined.
// 256 blocks = 32 chains x 8 slices (32 cells each). Iteration t computes
// layer0 step t (t<S) and layer1 step t-1 (t>=1). Cross-block h exchange as in
// round 1: one u64 atom = {tag | 2xfp16}, relaxed agent-scope atomics, 4-slot
// rings (skew <=1 proven: iter t needs ALL peers' iter-(t-1) publishes).
// Thread parts (128 each): 0,1 = Wh0 K-half 0/1; 2,3 = Wh1; 4,5 = Wi1 (layer1
// x-projection on h0 -> replaces layer-1 gemm_xp). All weights VGPR-resident.
__global__ __launch_bounds__(768) void lstm_fused(
    const uint32_t* __restrict__ Wh0,  // fp16-pair view [1024][128] layer0 Whh
    const uint32_t* __restrict__ Wh1,  // layer1 Whh
    const uint32_t* __restrict__ Wi1,  // layer1 Wih
    const half_t*  __restrict__ xp,    // [M][1024] packed [m][cell][4], layer0, biases folded
    const float*   __restrict__ bsum1, // [1024] layer1 bias sums
    unsigned long long* __restrict__ hp0,
    unsigned long long* __restrict__ hp1,
    float* __restrict__ out,           // [B][S][H] fp32 layer1 h sequence
    float* __restrict__ hT, float* __restrict__ cT)
{
  __shared__ __align__(16) uint32_t h0s[128];  // h0[t-1] pairs
  __shared__ __align__(16) uint32_t h1s[128];  // h1[t-2] pairs
  __shared__ float red[6][128];
  const int tid = threadIdx.x;
  const int part = tid >> 7;       // 0..5
  const int r    = tid & 127;      // row in slice: gate g = r>>5, cell cl = r&31
  const int kh   = part & 1;       // K-half
  const int b  = blockIdx.x & 31;
  const int s  = blockIdx.x >> 5;
  const int g  = r >> 5;
  const int cl = r & 31;
  const int cell = s*32 + cl;

  // VGPR-resident weights: row (g*256+cell) of my matrix, pairs [kh*64, kh*64+64)
  const uint32_t* wbase =
      (part < 2 ? Wh0 : (part < 4 ? Wh1 : Wi1)) + (size_t)(g*256 + cell)*128 + kh*64;
  uint32_t w[64];
  #pragma unroll
  for (int i=0;i<64;++i) w[i] = wbase[i];

  unsigned long long* r0 = hp0 + (size_t)b*(RING_R*128);
  unsigned long long* r1 = hp1 + (size_t)b*(RING_R*128);
  const size_t base = (size_t)b * S_N;

  float cst = 0.f;      // wave 0: lanes 0-31 hold layer0 c, lanes 32-63 layer1 c
  float bias0=0.f, bias1=0.f, bias2=0.f, bias3=0.f;   // lanes 32-63: layer1 biases
  if (tid >= 32 && tid < 64){
    const int mc = s*32 + (tid - 32);
    bias0 = bsum1[      mc];
    bias1 = bsum1[256 + mc];
    bias2 = bsum1[512 + mc];
    bias3 = bsum1[768 + mc];
  }

  for (int t=0; t<=S_N; ++t){
    // ---- phase 1: xp load (lanes 0-31) + ring polls -> LDS stage
    uint2 xv = {0u,0u};
    if (tid < 32 && t < S_N)
      xv = *(const uint2*)(xp + (base + t)*G_N + (size_t)(s*32 + tid)*4);
    if (tid < 128){
      if (t > 0){
        const unsigned long long v =
            ring_poll(r0 + (size_t)((t-1)&(RING_R-1))*128 + tid,
                      (unsigned long long)(unsigned)t);
        h0s[tid] = (uint32_t)v;
      } else h0s[tid] = 0u;
    } else if (tid < 256){
      const int j = tid - 128;
      if (t > 1){
        const unsigned long long v =
            ring_poll(r1 + (size_t)((t-2)&(RING_R-1))*128 + j,
                      (unsigned long long)(unsigned)(t-1));
        h1s[j] = (uint32_t)v;
      } else h1s[j] = 0u;
    }
    __syncthreads();                    // B1: h staged

    // ---- phase 2: fdot (64 pair-MACs per thread, 4 independent streams)
    const bool active = (part < 2) ? (t < S_N) : (t >= 1);
    if (active){
      const uint32_t* hsrc = (part == 2 || part == 3) ? h1s : h0s;
      const uint4* h4 = (const uint4*)(hsrc + kh*64);
      float a0=0.f,a1=0.f,a2=0.f,a3=0.f;
      #pragma unroll
      for (int i=0;i<16;++i){
        const uint4 hh = h4[i];
        a0 = __builtin_amdgcn_fdot2(__builtin_bit_cast(half2_t, w[4*i+0]), __builtin_bit_cast(half2_t, hh.x), a0, false);
        a1 = __builtin_amdgcn_fdot2(__builtin_bit_cast(half2_t, w[4*i+1]), __builtin_bit_cast(half2_t, hh.y), a1, false);
        a2 = __builtin_amdgcn_fdot2(__builtin_bit_cast(half2_t, w[4*i+2]), __builtin_bit_cast(half2_t, hh.z), a2, false);
        a3 = __builtin_amdgcn_fdot2(__builtin_bit_cast(half2_t, w[4*i+3]), __builtin_bit_cast(half2_t, hh.w), a3, false);
      }
      red[part][r] = (a0+a1)+(a2+a3);
    }
    __syncthreads();                    // B2: partials visible

    // ---- phase 3: wave 0 finishes both layers' cells, publishes, writes out
    if (tid < 64){
      const int half = tid >> 5;        // 0 = layer0 (step t), 1 = layer1 (step t-1)
      const int l = tid & 31;
      const int mc = s*32 + l;
      const bool act = half ? (t >= 1) : (t < S_N);
      if (act){
        float s0,s1,s2,s3;
        if (!half){
          const half2_t xlo = __builtin_bit_cast(half2_t, xv.x);
          const half2_t xhi = __builtin_bit_cast(half2_t, xv.y);
          s0 = red[0][     l] + red[1][     l] + (float)xlo.x;
          s1 = red[0][32 + l] + red[1][32 + l] + (float)xlo.y;
          s2 = red[0][64 + l] + red[1][64 + l] + (float)xhi.x;
          s3 = red[0][96 + l] + red[1][96 + l] + (float)xhi.y;
        } else {
          s0 = red[2][     l] + red[3][     l] + red[4][     l] + red[5][     l] + bias0;
          s1 = red[2][32 + l] + red[3][32 + l] + red[4][32 + l] + red[5][32 + l] + bias1;
          s2 = red[2][64 + l] + red[3][64 + l] + red[4][64 + l] + red[5][64 + l] + bias2;
          s3 = red[2][96 + l] + red[3][96 + l] + red[4][96 + l] + red[5][96 + l] + bias3;
        }
        const float gi = sigf(s0);
        const float gf = sigf(s1);
        const float gg = tanh_f(s2);
        const float go = sigf(s3);
        cst = gf*cst + gi*gg;
        const float h = go * tanh_f(cst);
        const half_t hv = (half_t)h;

        // publish tagged pairs (lanes with (l)<16 of each half store 16 u64)
        const int hu = (int)__builtin_bit_cast(unsigned short, hv);
        const int base2 = (tid & 32) | ((tid & 15) << 1);
        const int plo = __shfl(hu, base2,     64);
        const int phi = __shfl(hu, base2 + 1, 64);
        if (l < 16){
          const unsigned tag = half ? (unsigned)t : (unsigned)(t+1);   // step+1
          const unsigned long long val =
              ((unsigned long long)tag << 32)
            | (unsigned long long)((((unsigned)phi & 0xffffu) << 16) | ((unsigned)plo & 0xffffu));
          unsigned long long* dst = half
            ? r1 + (size_t)((t-1)&(RING_R-1))*128 + s*16 + l
            : r0 + (size_t)( t   &(RING_R-1))*128 + s*16 + l;
          __hip_atomic_store(dst, val, __ATOMIC_RELAXED, __HIP_MEMORY_SCOPE_AGENT);
        }
        if (half){
          out[(base + (t-1))*H_N + mc] = h;
          if (t-1 == S_N-1){ hT[B_N*H_N + b*H_N + mc] = h; cT[B_N*H_N + b*H_N + mc] = cst; }
        } else {
          if (t == S_N-1){ hT[b*H_N + mc] = h; cT[b*H_N + mc] = cst; }
        }
      }
    }
    // no trailing barrier needed: red is next written after B1(t+1); h0s/h1s
    // next written after B2(t) by phase-1(t+1), while all readers finished
    // their reads before reaching B2(t).
  }
}

extern "C" void kernel_launch(void* const* d_in, const int* in_sizes, int n_in,
                              void* d_out, int out_size, void* d_ws, size_t ws_size,
                              hipStream_t stream)
{
  const float* x   = (const float*)d_in[0];
  const float* Wih = (const float*)d_in[1];
  const float* bih = (const float*)d_in[2];
  const float* Whh = (const float*)d_in[3];
  const float* bhh = (const float*)d_in[4];
  float* out = (float*)d_out;

  char* ws = (char*)d_ws;
  half_t* A0   = (half_t*)(ws + WS_A0);
  half_t* XP   = (half_t*)(ws + WS_XP);
  half_t* Wi16 = (half_t*)(ws + WS_WI);
  half_t* Wh16 = (half_t*)(ws + WS_WH);
  float*  bsum = (float*)(ws + WS_BSUM);
  unsigned long long* hp0 = (unsigned long long*)(ws + WS_HP0);
  unsigned long long* hp1 = (unsigned long long*)(ws + WS_HP1);

  cvt_f32_f16<<<dim3(M_N*H_N/256), dim3(256), 0, stream>>>(x, A0, M_N*H_N);
  cvt_f32_f16<<<dim3(L_N*G_N*H_N/256), dim3(256), 0, stream>>>(Wih, Wi16, L_N*G_N*H_N);
  cvt_f32_f16<<<dim3(L_N*G_N*H_N/256), dim3(256), 0, stream>>>(Whh, Wh16, L_N*G_N*H_N);
  make_bsum<<<dim3(L_N*G_N/256), dim3(256), 0, stream>>>(bih, bhh, bsum, L_N*G_N);

  float* hT = out + (size_t)M_N*H_N;       // hs [2][32][256]
  float* cT = hT + (size_t)L_N*B_N*H_N;    // cs [2][32][256]

  // layer-0 input projection (layer-1's is fused into the recurrence kernel)
  gemm_xp<<<dim3(M_N/64, G_N/64), dim3(256), 0, stream>>>(A0, Wi16, bsum, XP);

  hipMemsetAsync(hp0, 0, 2*RING_BYTES, stream);   // hp0 + hp1 contiguous

  lstm_fused<<<dim3(B_N*8), dim3(768), 0, stream>>>(
      (const uint32_t*)Wh16,
      (const uint32_t*)(Wh16 + (size_t)G_N*H_N),
      (const uint32_t*)(Wi16 + (size_t)G_N*H_N),
      XP, bsum + G_N, hp0, hp1, out, hT, cT);
}